// Round 12
// baseline (199.345 us; speedup 1.0000x reference)
//
#include <hip/hip_runtime.h>

typedef unsigned short u16;
typedef unsigned int   u32;
typedef __attribute__((ext_vector_type(8))) __bf16 bf16x8;
typedef __attribute__((ext_vector_type(4))) float  f32x4;

#define L_SEQ  2048
#define BATCH  8
#define DIM    1024
#define ROWS   16384
#define N3     3072
#define NCHUNK 128
#define LCHUNK 16
#define NCHAIN 8192

struct __align__(8) us4 { u16 x, y, z, w; };

__device__ __forceinline__ float b2f(u16 h) {
  return __builtin_bit_cast(float, (u32)h << 16);
}
__device__ __forceinline__ u32 pk2(float a, float b) {
  u32 r;
  asm("v_cvt_pk_bf16_f32 %0, %1, %2" : "=v"(r) : "v"(a), "v"(b));
  return r;
}
__device__ __forceinline__ u16 f2b(float f) {
  u32 u = __builtin_bit_cast(u32, f);
  return (u16)((u + 0x7fffu + ((u >> 16) & 1u)) >> 16);
}
__device__ __forceinline__ f32x4 mf(bf16x8 a, bf16x8 b, f32x4 c) {
  return __builtin_amdgcn_mfma_f32_16x16x32_bf16(a, b, c, 0, 0, 0);
}

// ---------------- K0: pack x -> apk (256-row M-tiles, fg 0..15), W -> wpk ------
// A chunk ((mt*32+t)*16+fg)*64+lane : 8 u16 = x[mt*256+fg*16+(lane&15)][t*32+(lane>>4)*8 ..+8]
// B chunk ((nt*32+t)*16+c )*64+lane : 8 u16 = W[nt*256+c *16+(lane&15)][t*32+(lane>>4)*8 ..+8]
__global__ void k_pack(const float* __restrict__ x, const float* __restrict__ W,
                       u16* __restrict__ apk, u16* __restrict__ wpk) {
  const int NA = 64 * 32 * 16 * 64;   // 2097152 chunks of 8 u16
  const int NB = 12 * 32 * 16 * 64;   // 393216
  int i = blockIdx.x * 256 + threadIdx.x;
  const int stride = gridDim.x * 256;
  for (; i < NA + NB; i += stride) {
    const float* src; u16* dst;
    if (i < NA) {
      int lane = i & 63, fg = (i >> 6) & 15, t = (i >> 10) & 31, mt = i >> 15;
      int row = mt * 256 + fg * 16 + (lane & 15);
      int k   = t * 32 + (lane >> 4) * 8;
      src = x + (size_t)row * DIM + k;
      dst = apk + (size_t)i * 8;
    } else {
      int j = i - NA;
      int lane = j & 63, c = (j >> 6) & 15, t = (j >> 10) & 31, nt = j >> 15;
      int col = nt * 256 + c * 16 + (lane & 15);
      int k   = t * 32 + (lane >> 4) * 8;
      src = W + (size_t)col * DIM + k;
      dst = wpk + (size_t)j * 8;
    }
    float4 v0 = *(const float4*)src;
    float4 v1 = *(const float4*)(src + 4);
    uint4 o;
    o.x = pk2(v0.x, v0.y); o.y = pk2(v0.z, v0.w);
    o.z = pk2(v1.x, v1.y); o.w = pk2(v1.z, v1.w);
    *(uint4*)dst = o;
  }
}

// ---------------- K1: 256x256 8-phase-style GEMM, both operands LDS ping-pong --
__device__ __forceinline__ void gl_lds16(const u16* g, u16* l) {
  __builtin_amdgcn_global_load_lds((const __attribute__((address_space(1))) void*)g,
                                   (__attribute__((address_space(3))) void*)l,
                                   16, 0, 0);
}

__global__ __launch_bounds__(512, 2) void k_gemm_v8(const u16* __restrict__ apk,
                                                    const u16* __restrict__ wpk,
                                                    u16* __restrict__ C) {
  // LDS (u16 offsets): A buf p at p*8192 (+mh*4096+fg'*512+lane*8)
  //                    B buf p at 16384 + p*8192 (+nh*4096+fg'*512+lane*8)
  __shared__ u16 lds[32768];                      // 64 KiB
  const int tid  = threadIdx.x;
  const int lane = tid & 63;
  const int wid  = tid >> 6;                      // 8 waves: wm 0..1, wn 0..3
  const int wm = wid >> 2, wn = wid & 3;
  const int lr = lane & 15, lk = lane >> 4;

  const int bid = blockIdx.x;                     // 768 = 8 XCD * 96
  const int xcd = bid & 7;
  const int r   = bid >> 3;                       // 0..95
  const int byl = r / 12;                         // 0..7
  const int bx  = r - byl * 12;                   // 0..11 N-panel
  const int by  = xcd * 8 + byl;                  // 0..63 M-tile (256 rows)

  // per-thread staging bases (fg = wid for first issue, 8+wid for second)
  const u16* apkA = apk + (((size_t)by * 32 * 16 + wid) * 64 + lane) * 8;
  const u16* wpkB = wpk + (((size_t)bx * 32 * 16 + wid) * 64 + lane) * 8;
  u16* ldsT = &lds[wid * 512 + lane * 8];

  // read bases
  const u16* aB = &lds[wm * 4096 + lane * 8];
  const u16* bB = &lds[16384 + (wn >> 1) * 4096 + (wn & 1) * 2048 + lane * 8];

  f32x4 acc[8][4] = {};

#define STAGE_A(T, SB) { \
    gl_lds16(apkA + (size_t)(T) * 8192,            ldsT + (SB));          \
    gl_lds16(apkA + (size_t)(T) * 8192 + 4096,     ldsT + (SB) + 4096); }
#define STAGE_B(T, SB) { \
    gl_lds16(wpkB + (size_t)(T) * 8192,            ldsT + 16384 + (SB));          \
    gl_lds16(wpkB + (size_t)(T) * 8192 + 4096,     ldsT + 16384 + (SB) + 4096); }

#define MFMA16(M4, a0,a1,a2,a3) \
    acc[(M4)+0][0]=mf(a0,b0,acc[(M4)+0][0]); acc[(M4)+0][1]=mf(a0,b1,acc[(M4)+0][1]); \
    acc[(M4)+0][2]=mf(a0,b2,acc[(M4)+0][2]); acc[(M4)+0][3]=mf(a0,b3,acc[(M4)+0][3]); \
    acc[(M4)+1][0]=mf(a1,b0,acc[(M4)+1][0]); acc[(M4)+1][1]=mf(a1,b1,acc[(M4)+1][1]); \
    acc[(M4)+1][2]=mf(a1,b2,acc[(M4)+1][2]); acc[(M4)+1][3]=mf(a1,b3,acc[(M4)+1][3]); \
    acc[(M4)+2][0]=mf(a2,b0,acc[(M4)+2][0]); acc[(M4)+2][1]=mf(a2,b1,acc[(M4)+2][1]); \
    acc[(M4)+2][2]=mf(a2,b2,acc[(M4)+2][2]); acc[(M4)+2][3]=mf(a2,b3,acc[(M4)+2][3]); \
    acc[(M4)+3][0]=mf(a3,b0,acc[(M4)+3][0]); acc[(M4)+3][1]=mf(a3,b1,acc[(M4)+3][1]); \
    acc[(M4)+3][2]=mf(a3,b2,acc[(M4)+3][2]); acc[(M4)+3][3]=mf(a3,b3,acc[(M4)+3][3]);

  // PHASE0: verify-at-head phase (stage -> counted vmcnt -> barrier -> reads)
#define PHASE0(RB, STG, VM) { \
    STG \
    __builtin_amdgcn_sched_barrier(0); \
    if ((VM) == 1) asm volatile("s_waitcnt vmcnt(2)" ::: "memory"); \
    else           asm volatile("s_waitcnt vmcnt(0)" ::: "memory"); \
    asm volatile("s_barrier" ::: "memory"); \
    const u16* ab_ = aB + (RB); \
    bf16x8 a0 = *(const bf16x8*)(ab_); \
    bf16x8 a1 = *(const bf16x8*)(ab_ + 512); \
    bf16x8 a2 = *(const bf16x8*)(ab_ + 1024); \
    bf16x8 a3 = *(const bf16x8*)(ab_ + 1536); \
    const u16* bb_ = bB + (RB); \
    bf16x8 b0 = *(const bf16x8*)(bb_); \
    bf16x8 b1 = *(const bf16x8*)(bb_ + 512); \
    bf16x8 b2 = *(const bf16x8*)(bb_ + 1024); \
    bf16x8 b3 = *(const bf16x8*)(bb_ + 1536); \
    asm volatile("s_waitcnt lgkmcnt(0)" ::: "memory"); \
    __builtin_amdgcn_sched_barrier(0); \
    __builtin_amdgcn_s_setprio(1); \
    MFMA16(0, a0, a1, a2, a3) \
    __builtin_amdgcn_s_setprio(0); \
    asm volatile("s_barrier" ::: "memory"); \
  }

  // PHASEX: steady phase (reads issued early, overlap leading barrier)
#define PHASEX(RB, STG) { \
    const u16* ab_ = aB + (RB) + 2048; \
    bf16x8 a0 = *(const bf16x8*)(ab_); \
    bf16x8 a1 = *(const bf16x8*)(ab_ + 512); \
    bf16x8 a2 = *(const bf16x8*)(ab_ + 1024); \
    bf16x8 a3 = *(const bf16x8*)(ab_ + 1536); \
    const u16* bb_ = bB + (RB); \
    bf16x8 b0 = *(const bf16x8*)(bb_); \
    bf16x8 b1 = *(const bf16x8*)(bb_ + 512); \
    bf16x8 b2 = *(const bf16x8*)(bb_ + 1024); \
    bf16x8 b3 = *(const bf16x8*)(bb_ + 1536); \
    __builtin_amdgcn_sched_barrier(0); \
    STG \
    __builtin_amdgcn_sched_barrier(0); \
    asm volatile("s_barrier" ::: "memory"); \
    asm volatile("s_waitcnt lgkmcnt(0)" ::: "memory"); \
    __builtin_amdgcn_sched_barrier(0); \
    __builtin_amdgcn_s_setprio(1); \
    MFMA16(4, a0, a1, a2, a3) \
    __builtin_amdgcn_s_setprio(0); \
    asm volatile("s_barrier" ::: "memory"); \
  }

  // prologue: stage tile 0 -> buf 0 (4 loads/thread)
  STAGE_A(0, 0)
  STAGE_B(0, 0)

  for (int t = 0; t < 31; ++t) {
    const int RB = (t & 1) * 8192;
    const int SB = RB ^ 8192;
    PHASE0(RB, STAGE_A(t + 1, SB), 1)     // MQ0 + verify tile t (vmcnt 2)
    PHASEX(RB, STAGE_B(t + 1, SB))        // MQ1
  }
  PHASE0(8192, {}, 0)                     // t=31: drain (vmcnt 0)
  PHASEX(8192, {})
#undef PHASE0
#undef PHASEX
#undef MFMA16
#undef STAGE_A
#undef STAGE_B

  const bool act = (bx >= 4);                     // f/r panels -> sigmoid
#pragma unroll
  for (int m = 0; m < 8; ++m) {
    const int row0 = by * 256 + wm * 128 + m * 16 + lk * 4;
#pragma unroll
    for (int n = 0; n < 4; ++n) {
      const int col = bx * 256 + wn * 64 + n * 16 + lr;
#pragma unroll
      for (int j = 0; j < 4; ++j) {
        float v = acc[m][n][j];
        if (act) v = 1.f / (1.f + __expf(-v));
        C[(size_t)(row0 + j) * N3 + col] = f2b(v);
      }
    }
  }
}

// ---------------- K1 fallback: f32-input reg-staged GEMM (validated r1) --------
__global__ __launch_bounds__(256) void k_gemm_reg(const float* __restrict__ A,
                                                  const float* __restrict__ B,
                                                  u16* __restrict__ C) {
  __shared__ u16 lds[8192];
  const int tid  = threadIdx.x;
  const int lane = tid & 63;
  const int wid  = tid >> 6;
  const int wm = wid >> 1, wn = wid & 1;
  const int lr = lane & 15, lk = lane >> 4;
  const int mBase = blockIdx.y << 7;
  const int nBase = blockIdx.x << 7;

  f32x4 acc[4][4] = {};
  const int aoff = (wm * 64 + lr) * 32 + lk * 8;
  const int boff = 4096 + (wn * 64 + lr) * 32 + lk * 8;

  for (int k0 = 0; k0 < DIM; k0 += 32) {
#pragma unroll
    for (int q = 0; q < 4; ++q) {
      const int i  = q * 256 + tid;
      const int rr = i >> 3;
      const int cc = (i & 7) << 2;
      float4 va = *(const float4*)(A + (size_t)(mBase + rr) * DIM + k0 + cc);
      float4 vb = *(const float4*)(B + (size_t)(nBase + rr) * DIM + k0 + cc);
      uint2 pa; pa.x = pk2(va.x, va.y); pa.y = pk2(va.z, va.w);
      uint2 pb; pb.x = pk2(vb.x, vb.y); pb.y = pk2(vb.z, vb.w);
      *(uint2*)&lds[rr * 32 + cc] = pa;
      *(uint2*)&lds[4096 + rr * 32 + cc] = pb;
    }
    __syncthreads();
    bf16x8 av[4], bv[4];
#pragma unroll
    for (int m = 0; m < 4; ++m) av[m] = *(const bf16x8*)&lds[aoff + m * 512];
#pragma unroll
    for (int n = 0; n < 4; ++n) bv[n] = *(const bf16x8*)&lds[boff + n * 512];
#pragma unroll
    for (int m = 0; m < 4; ++m)
#pragma unroll
      for (int n = 0; n < 4; ++n)
        acc[m][n] = mf(av[m], bv[n], acc[m][n]);
    __syncthreads();
  }

  const bool act = (nBase >= DIM);
#pragma unroll
  for (int m = 0; m < 4; ++m) {
    const int row0 = mBase + wm * 64 + m * 16 + lk * 4;
#pragma unroll
    for (int n = 0; n < 4; ++n) {
      const int col = nBase + wn * 64 + n * 16 + lr;
#pragma unroll
      for (int j = 0; j < 4; ++j) {
        float v = acc[m][n][j];
        if (act) v = 1.f / (1.f + __expf(-v));
        C[(size_t)(row0 + j) * N3 + col] = f2b(v);
      }
    }
  }
}

// ---------------- K2: chunk-local affine coefficients (4 chains/thread) --------
__global__ void k_scanA(const u16* __restrict__ ufr, float* __restrict__ P,
                        float* __restrict__ V) {
  int idx = blockIdx.x * 256 + threadIdx.x;       // 0..262143
  int j  = idx >> 11;                             // chunk 0..127
  int cg = idx & 2047;
  int b  = cg >> 8;                               // 0..7
  int d0 = (cg & 255) << 2;                       // 0,4,...,1020
  const u16* p = ufr + (size_t)((j * LCHUNK) * BATCH + b) * N3 + d0;
  float prod0 = 1.f, prod1 = 1.f, prod2 = 1.f, prod3 = 1.f;
  float v0 = 0.f, v1 = 0.f, v2 = 0.f, v3 = 0.f;
  for (int t = 0; t < LCHUNK; ++t) {
    us4 uu = *(const us4*)(p);
    us4 ff = *(const us4*)(p + DIM);
    float f0 = b2f(ff.x), f1 = b2f(ff.y), f2 = b2f(ff.z), f3 = b2f(ff.w);
    v0 = f0 * v0 + (1.f - f0) * b2f(uu.x); prod0 *= f0;
    v1 = f1 * v1 + (1.f - f1) * b2f(uu.y); prod1 *= f1;
    v2 = f2 * v2 + (1.f - f2) * b2f(uu.z); prod2 *= f2;
    v3 = f3 * v3 + (1.f - f3) * b2f(uu.w); prod3 *= f3;
    p += BATCH * N3;
  }
  const int base = j * NCHAIN + b * DIM + d0;
  *(float4*)&P[base] = make_float4(prod0, prod1, prod2, prod3);
  *(float4*)&V[base] = make_float4(v0, v1, v2, v3);
}

// ---------------- K3: sequential combine over chunks ---------------------------
__global__ void k_scanB(const float* __restrict__ c0, const float* __restrict__ P,
                        const float* __restrict__ V, float* __restrict__ S,
                        float* __restrict__ lastc) {
  int chain = blockIdx.x * 256 + threadIdx.x;     // 0..8191
  float c = c0[chain];
  for (int j = 0; j < NCHUNK; ++j) {
    S[j * NCHAIN + chain] = c;
    c = P[j * NCHAIN + chain] * c + V[j * NCHAIN + chain];
  }
  lastc[chain] = c;
}

// ---------------- K4: fused replay + hs + gelu + LayerNorm (vectorized x4) -----
__global__ __launch_bounds__(256) void k_scanln(const u16* __restrict__ ufr,
                                                const float* __restrict__ S,
                                                const float* __restrict__ x,
                                                const float* __restrict__ lnw,
                                                const float* __restrict__ lnb,
                                                float* __restrict__ out) {
  const int j = blockIdx.x >> 3;                  // chunk 0..127
  const int b = blockIdx.x & 7;                   // batch
  const int tid = threadIdx.x;                    // 0..255
  const int d0 = tid << 2;
  const int lane = tid & 63, wid = tid >> 6;      // 4 waves

  float4 c4  = *(const float4*)&S[j * NCHAIN + b * DIM + d0];
  float c0v = c4.x, c1v = c4.y, c2v = c4.z, c3v = c4.w;
  const float4 wv = *(const float4*)(lnw + d0);
  const float4 bv = *(const float4*)(lnb + d0);

  const u16*   pu = ufr + (size_t)((j * LCHUNK) * BATCH + b) * N3 + d0;
  const float* px = x   + (size_t)((j * LCHUNK) * BATCH + b) * DIM + d0;
  float*       po = out + (size_t)((j * LCHUNK) * BATCH + b) * DIM + d0;

  __shared__ float red1[2][4], red2[2][4];

  us4 cu = *(const us4*)(pu);
  us4 cf = *(const us4*)(pu + DIM);
  us4 cr = *(const us4*)(pu + 2 * DIM);
  float4 cx = *(const float4*)px;

  for (int t = 0; t < LCHUNK; ++t) {
    const size_t advU = (t < LCHUNK - 1) ? (size_t)BATCH * N3 : 0;
    const size_t advX = (t < LCHUNK - 1) ? (size_t)BATCH * DIM : 0;
    us4 nu = *(const us4*)(pu + advU);
    us4 nf = *(const us4*)(pu + advU + DIM);
    us4 nr = *(const us4*)(pu + advU + 2 * DIM);
    float4 nx = *(const float4*)(px + advX);

    float g0, g1, g2, g3;
    {
      float f = b2f(cf.x); c0v = f * c0v + (1.f - f) * b2f(cu.x);
      float rr = b2f(cr.x);
      float hs = rr * tanhf(c0v) + (1.f - rr) * cx.x;
      g0 = 0.5f * hs * (1.f + erff(hs * 0.70710678118654752f));
    }
    {
      float f = b2f(cf.y); c1v = f * c1v + (1.f - f) * b2f(cu.y);
      float rr = b2f(cr.y);
      float hs = rr * tanhf(c1v) + (1.f - rr) * cx.y;
      g1 = 0.5f * hs * (1.f + erff(hs * 0.70710678118654752f));
    }
    {
      float f = b2f(cf.z); c2v = f * c2v + (1.f - f) * b2f(cu.z);
      float rr = b2f(cr.z);
      float hs = rr * tanhf(c2v) + (1.f - rr) * cx.z;
      g2 = 0.5f * hs * (1.f + erff(hs * 0.70710678118654752f));
    }
    {
      float f = b2f(cf.w); c3v = f * c3v + (1.f - f) * b2f(cu.w);
      float rr = b2f(cr.w);
      float hs = rr * tanhf(c3v) + (1.f - rr) * cx.w;
      g3 = 0.5f * hs * (1.f + erff(hs * 0.70710678118654752f));
    }

    float s1 = g0 + g1 + g2 + g3;
    float s2 = g0 * g0 + g1 * g1 + g2 * g2 + g3 * g3;
#pragma unroll
    for (int off = 32; off > 0; off >>= 1) {
      s1 += __shfl_down(s1, off, 64);
      s2 += __shfl_down(s2, off, 64);
    }
    const int pb = t & 1;
    if (lane == 0) { red1[pb][wid] = s1; red2[pb][wid] = s2; }
    __syncthreads();
    float S1 = red1[pb][0] + red1[pb][1] + red1[pb][2] + red1[pb][3];
    float S2 = red2[pb][0] + red2[pb][1] + red2[pb][2] + red2[pb][3];
    float mu  = S1 * (1.f / DIM);
    float var = S2 * (1.f / DIM) - mu * mu;
    float inv = rsqrtf(var + 1e-5f);
    float4 o;
    o.x = (g0 - mu) * inv * wv.x + bv.x;
    o.y = (g1 - mu) * inv * wv.y + bv.y;
    o.z = (g2 - mu) * inv * wv.z + bv.z;
    o.w = (g3 - mu) * inv * wv.w + bv.w;
    *(float4*)po = o;

    cu = nu; cf = nf; cr = nr; cx = nx;
    pu += BATCH * N3;
    px += BATCH * DIM;
    po += BATCH * DIM;
  }
}

extern "C" void kernel_launch(void* const* d_in, const int* in_sizes, int n_in,
                              void* d_out, int out_size, void* d_ws, size_t ws_size,
                              hipStream_t stream) {
  (void)in_sizes; (void)n_in; (void)out_size;
  const float* x   = (const float*)d_in[0];
  const float* c0  = (const float*)d_in[1];
  const float* W   = (const float*)d_in[2];
  const float* lnw = (const float*)d_in[3];
  const float* lnb = (const float*)d_in[4];
  float* out   = (float*)d_out;                   // (L,B,D) f32
  float* lastc = out + (size_t)ROWS * DIM;        // (B,D)   f32

  char* ws = (char*)d_ws;

  u16* ufr; float *P, *V, *S;
  const size_t FULL_NEED = 140509184;             // apk + wpk + ufr (P/V/S alias apk)
  if (ws_size >= FULL_NEED) {
    u16* apk = (u16*)ws;                          // 33,554,432 B (dead after GEMM)
    u16* wpk = (u16*)(ws + 33554432);             //  6,291,456 B
    ufr = (u16*)(ws + 39845888);                  // 100,663,296 B
    P   = (float*)ws;                             // alias apk region (4 MB each)
    V   = (float*)(ws + 4194304);
    S   = (float*)(ws + 8388608);
    k_pack<<<2048, 256, 0, stream>>>(x, W, apk, wpk);
    k_gemm_v8<<<768, 512, 0, stream>>>(apk, wpk, ufr);
  } else {
    ufr = (u16*)ws;
    P   = (float*)(ws + 100663296);
    V   = (float*)(ws + 104857600);
    S   = (float*)(ws + 109051904);
    dim3 g1(N3 / 128, ROWS / 128);
    k_gemm_reg<<<g1, 256, 0, stream>>>(x, W, ufr);
  }

  k_scanA<<<1024, 256, 0, stream>>>(ufr, P, V);
  k_scanB<<<NCHAIN / 256, 256, 0, stream>>>(c0, P, V, S, lastc);
  k_scanln<<<NCHUNK * BATCH, 256, 0, stream>>>(ufr, S, x, lnw, lnb, out);
}

// Round 13
// 189.605 us; speedup vs baseline: 1.0514x; 1.0514x over previous
//
#include <hip/hip_runtime.h>

typedef unsigned short u16;
typedef unsigned int   u32;
typedef __attribute__((ext_vector_type(8))) __bf16 bf16x8;
typedef __attribute__((ext_vector_type(4))) float  f32x4;

#define L_SEQ  2048
#define BATCH  8
#define DIM    1024
#define ROWS   16384
#define N3     3072
#define NCHUNK 128
#define LCHUNK 16
#define NCHAIN 8192

struct __align__(8) us4 { u16 x, y, z, w; };

__device__ __forceinline__ float b2f(u16 h) {
  return __builtin_bit_cast(float, (u32)h << 16);
}
__device__ __forceinline__ u32 pk2(float a, float b) {
  u32 r;
  asm("v_cvt_pk_bf16_f32 %0, %1, %2" : "=v"(r) : "v"(a), "v"(b));
  return r;
}
__device__ __forceinline__ u16 f2b(float f) {
  u32 u = __builtin_bit_cast(u32, f);
  return (u16)((u + 0x7fffu + ((u >> 16) & 1u)) >> 16);
}
__device__ __forceinline__ f32x4 mf(bf16x8 a, bf16x8 b, f32x4 c) {
  return __builtin_amdgcn_mfma_f32_16x16x32_bf16(a, b, c, 0, 0, 0);
}

// ---------------- K0: pack x -> apk, W -> wpk in MFMA-frag order ---------------
// A chunk ca = ((mt*32+t)*8+fg)*64+lane : 8 u16 = x[mt*128+fg*16+(lane&15)][t*32+(lane>>4)*8 ..+8]
// B chunk cb = ((nt*32+t)*16+c)*64+lane : 8 u16 = W[nt*256+c*16+(lane&15)][t*32+(lane>>4)*8 ..+8]
__global__ void k_pack(const float* __restrict__ x, const float* __restrict__ W,
                       u16* __restrict__ apk, u16* __restrict__ wpk) {
  const int NA = 128 * 32 * 8 * 64;   // 2097152 chunks of 8 u16
  const int NB = 12 * 32 * 16 * 64;   // 393216
  int i = blockIdx.x * 256 + threadIdx.x;
  const int stride = gridDim.x * 256;
  for (; i < NA + NB; i += stride) {
    const float* src; u16* dst;
    if (i < NA) {
      int lane = i & 63, fg = (i >> 6) & 7, t = (i >> 9) & 31, mt = i >> 14;
      int row = mt * 128 + fg * 16 + (lane & 15);
      int k   = t * 32 + (lane >> 4) * 8;
      src = x + (size_t)row * DIM + k;
      dst = apk + (size_t)i * 8;
    } else {
      int j = i - NA;
      int lane = j & 63, c = (j >> 6) & 15, t = (j >> 10) & 31, nt = j >> 15;
      int col = nt * 256 + c * 16 + (lane & 15);
      int k   = t * 32 + (lane >> 4) * 8;
      src = W + (size_t)col * DIM + k;
      dst = wpk + (size_t)j * 8;
    }
    float4 v0 = *(const float4*)src;
    float4 v1 = *(const float4*)(src + 4);
    uint4 o;
    o.x = pk2(v0.x, v0.y); o.y = pk2(v0.z, v0.w);
    o.z = pk2(v1.x, v1.y); o.w = pk2(v1.z, v1.w);
    *(uint4*)dst = o;
  }
}

// ---------------- K1: GEMM (v6 structure; B-panel-resident XCD mapping) --------
__device__ __forceinline__ void gl_lds16(const u16* g, u16* l) {
  __builtin_amdgcn_global_load_lds((const __attribute__((address_space(1))) void*)g,
                                   (__attribute__((address_space(3))) void*)l,
                                   16, 0, 0);
}

__global__ __launch_bounds__(512, 4) void k_gemm_v6b(const u16* __restrict__ apk,
                                                     const u16* __restrict__ wpk,
                                                     u16* __restrict__ C) {
  __shared__ u16 lds[12288];                      // 3 slots x 8 KB (A tile 128x32)
  const int tid  = threadIdx.x;
  const int lane = tid & 63;
  const int wid  = tid >> 6;                      // 8 waves: wm 0..1, wn 0..3
  const int wm = wid >> 2, wn = wid & 3;
  const int lr = lane & 15, lk = lane >> 4;

  const int bid = blockIdx.x;                     // 1536 = 8 XCD * 192
  const int xcd = bid & 7;
  const int r   = bid >> 3;                       // 0..191
  const int bx  = r >> 4;                         // 0..11  N SLOW-varying (B L2-resident)
  const int byl = r & 15;                         // 0..15  M fast-varying
  const int by  = xcd * 16 + byl;

  const u16* srcA = apk + ((((size_t)by * 32) * 8 + wid) * 64 + lane) * 8;
  const u16* srcB = wpk + ((((size_t)bx * 32) * 16 + wn * 4) * 64 + lane) * 8;

  u16* d0 = &lds[wid * 512 + lane * 8];
  u16* d1 = d0 + 4096;
  u16* d2 = d0 + 8192;
  const u16* ldsA = &lds[wm * 2048 + lane * 8];

  f32x4 acc[4][4] = {};
  bf16x8 A0, A1, A2, A3, B0, B1, B2, B3;

  {
    const u16* gb = srcB;
    A0 = *(const bf16x8*)(gb);
    A1 = *(const bf16x8*)(gb + 512);
    A2 = *(const bf16x8*)(gb + 1024);
    A3 = *(const bf16x8*)(gb + 1536);
  }
  __builtin_amdgcn_sched_barrier(0);
  gl_lds16(srcA, d0);
  gl_lds16(srcA + 4096, d1);
  asm volatile("s_waitcnt vmcnt(1)" ::: "memory");
  asm volatile("s_barrier" ::: "memory");

#define GBODY(T, RB, DN, U0,U1,U2,U3, L0,L1,L2,L3, LOADB, STAGEA, LASTP) {   \
    if (STAGEA) gl_lds16(srcA + (size_t)((T) + 2) * 4096, DN);               \
    __builtin_amdgcn_sched_barrier(0);                                       \
    if (LOADB) {                                                             \
      const u16* gb_ = srcB + (size_t)((T) + 1) * 8192;                      \
      L0 = *(const bf16x8*)(gb_);                                            \
      L1 = *(const bf16x8*)(gb_ + 512);                                      \
      L2 = *(const bf16x8*)(gb_ + 1024);                                     \
      L3 = *(const bf16x8*)(gb_ + 1536);                                     \
    }                                                                        \
    __builtin_amdgcn_sched_barrier(0);                                       \
    const u16* rb_ = ldsA + (RB) * 4096;                                     \
    bf16x8 av0 = *(const bf16x8*)(rb_);                                      \
    bf16x8 av1 = *(const bf16x8*)(rb_ + 512);                                \
    bf16x8 av2 = *(const bf16x8*)(rb_ + 1024);                               \
    bf16x8 av3 = *(const bf16x8*)(rb_ + 1536);                               \
    __builtin_amdgcn_s_setprio(1);                                           \
    acc[0][0]=mf(av0,U0,acc[0][0]); acc[0][1]=mf(av0,U1,acc[0][1]);          \
    acc[0][2]=mf(av0,U2,acc[0][2]); acc[0][3]=mf(av0,U3,acc[0][3]);          \
    acc[1][0]=mf(av1,U0,acc[1][0]); acc[1][1]=mf(av1,U1,acc[1][1]);          \
    acc[1][2]=mf(av1,U2,acc[1][2]); acc[1][3]=mf(av1,U3,acc[1][3]);          \
    acc[2][0]=mf(av2,U0,acc[2][0]); acc[2][1]=mf(av2,U1,acc[2][1]);          \
    acc[2][2]=mf(av2,U2,acc[2][2]); acc[2][3]=mf(av2,U3,acc[2][3]);          \
    acc[3][0]=mf(av3,U0,acc[3][0]); acc[3][1]=mf(av3,U1,acc[3][1]);          \
    acc[3][2]=mf(av3,U2,acc[3][2]); acc[3][3]=mf(av3,U3,acc[3][3]);          \
    __builtin_amdgcn_s_setprio(0);                                           \
    if (!(LASTP)) asm volatile("s_barrier" ::: "memory");                    \
  }

  for (int t6 = 0; t6 < 30; t6 += 6) {
    GBODY(t6 + 0, 0, d2, A0,A1,A2,A3, B0,B1,B2,B3, 1, 1, 0)
    GBODY(t6 + 1, 1, d0, B0,B1,B2,B3, A0,A1,A2,A3, 1, 1, 0)
    GBODY(t6 + 2, 2, d1, A0,A1,A2,A3, B0,B1,B2,B3, 1, 1, 0)
    GBODY(t6 + 3, 0, d2, B0,B1,B2,B3, A0,A1,A2,A3, 1, 1, 0)
    GBODY(t6 + 4, 1, d0, A0,A1,A2,A3, B0,B1,B2,B3, 1, 1, 0)
    GBODY(t6 + 5, 2, d1, B0,B1,B2,B3, A0,A1,A2,A3, 1, 1, 0)
  }
  GBODY(30, 0, d2, A0,A1,A2,A3, B0,B1,B2,B3, 1, 0, 0)
  GBODY(31, 1, d0, B0,B1,B2,B3, A0,A1,A2,A3, 0, 0, 1)
#undef GBODY

  const bool act = (bx >= 4);
#pragma unroll
  for (int m = 0; m < 4; ++m) {
    const int row0 = by * 128 + wm * 64 + m * 16 + lk * 4;
#pragma unroll
    for (int n = 0; n < 4; ++n) {
      const int col = bx * 256 + wn * 64 + n * 16 + lr;
#pragma unroll
      for (int j = 0; j < 4; ++j) {
        float v = acc[m][n][j];
        if (act) v = 1.f / (1.f + __expf(-v));
        C[(size_t)(row0 + j) * N3 + col] = f2b(v);
      }
    }
  }
}

// ---------------- K1 fallback: f32-input reg-staged GEMM (validated r1) --------
__global__ __launch_bounds__(256) void k_gemm_reg(const float* __restrict__ A,
                                                  const float* __restrict__ B,
                                                  u16* __restrict__ C) {
  __shared__ u16 lds[8192];
  const int tid  = threadIdx.x;
  const int lane = tid & 63;
  const int wid  = tid >> 6;
  const int wm = wid >> 1, wn = wid & 1;
  const int lr = lane & 15, lk = lane >> 4;
  const int mBase = blockIdx.y << 7;
  const int nBase = blockIdx.x << 7;

  f32x4 acc[4][4] = {};
  const int aoff = (wm * 64 + lr) * 32 + lk * 8;
  const int boff = 4096 + (wn * 64 + lr) * 32 + lk * 8;

  for (int k0 = 0; k0 < DIM; k0 += 32) {
#pragma unroll
    for (int q = 0; q < 4; ++q) {
      const int i  = q * 256 + tid;
      const int rr = i >> 3;
      const int cc = (i & 7) << 2;
      float4 va = *(const float4*)(A + (size_t)(mBase + rr) * DIM + k0 + cc);
      float4 vb = *(const float4*)(B + (size_t)(nBase + rr) * DIM + k0 + cc);
      uint2 pa; pa.x = pk2(va.x, va.y); pa.y = pk2(va.z, va.w);
      uint2 pb; pb.x = pk2(vb.x, vb.y); pb.y = pk2(vb.z, vb.w);
      *(uint2*)&lds[rr * 32 + cc] = pa;
      *(uint2*)&lds[4096 + rr * 32 + cc] = pb;
    }
    __syncthreads();
    bf16x8 av[4], bv[4];
#pragma unroll
    for (int m = 0; m < 4; ++m) av[m] = *(const bf16x8*)&lds[aoff + m * 512];
#pragma unroll
    for (int n = 0; n < 4; ++n) bv[n] = *(const bf16x8*)&lds[boff + n * 512];
#pragma unroll
    for (int m = 0; m < 4; ++m)
#pragma unroll
      for (int n = 0; n < 4; ++n)
        acc[m][n] = mf(av[m], bv[n], acc[m][n]);
    __syncthreads();
  }

  const bool act = (nBase >= DIM);
#pragma unroll
  for (int m = 0; m < 4; ++m) {
    const int row0 = mBase + wm * 64 + m * 16 + lk * 4;
#pragma unroll
    for (int n = 0; n < 4; ++n) {
      const int col = nBase + wn * 64 + n * 16 + lr;
#pragma unroll
      for (int j = 0; j < 4; ++j) {
        float v = acc[m][n][j];
        if (act) v = 1.f / (1.f + __expf(-v));
        C[(size_t)(row0 + j) * N3 + col] = f2b(v);
      }
    }
  }
}

// ---------------- K2: chunk-local affine coefficients (4 chains/thread) --------
__global__ void k_scanA(const u16* __restrict__ ufr, float* __restrict__ P,
                        float* __restrict__ V) {
  int idx = blockIdx.x * 256 + threadIdx.x;       // 0..262143
  int j  = idx >> 11;                             // chunk 0..127
  int cg = idx & 2047;
  int b  = cg >> 8;                               // 0..7
  int d0 = (cg & 255) << 2;                       // 0,4,...,1020
  const u16* p = ufr + (size_t)((j * LCHUNK) * BATCH + b) * N3 + d0;
  float prod0 = 1.f, prod1 = 1.f, prod2 = 1.f, prod3 = 1.f;
  float v0 = 0.f, v1 = 0.f, v2 = 0.f, v3 = 0.f;
  for (int t = 0; t < LCHUNK; ++t) {
    us4 uu = *(const us4*)(p);
    us4 ff = *(const us4*)(p + DIM);
    float f0 = b2f(ff.x), f1 = b2f(ff.y), f2 = b2f(ff.z), f3 = b2f(ff.w);
    v0 = f0 * v0 + (1.f - f0) * b2f(uu.x); prod0 *= f0;
    v1 = f1 * v1 + (1.f - f1) * b2f(uu.y); prod1 *= f1;
    v2 = f2 * v2 + (1.f - f2) * b2f(uu.z); prod2 *= f2;
    v3 = f3 * v3 + (1.f - f3) * b2f(uu.w); prod3 *= f3;
    p += BATCH * N3;
  }
  const int base = j * NCHAIN + b * DIM + d0;
  *(float4*)&P[base] = make_float4(prod0, prod1, prod2, prod3);
  *(float4*)&V[base] = make_float4(v0, v1, v2, v3);
}

// ---------------- K3: sequential combine over chunks ---------------------------
__global__ void k_scanB(const float* __restrict__ c0, const float* __restrict__ P,
                        const float* __restrict__ V, float* __restrict__ S,
                        float* __restrict__ lastc) {
  int chain = blockIdx.x * 256 + threadIdx.x;     // 0..8191
  float c = c0[chain];
  for (int j = 0; j < NCHUNK; ++j) {
    S[j * NCHAIN + chain] = c;
    c = P[j * NCHAIN + chain] * c + V[j * NCHAIN + chain];
  }
  lastc[chain] = c;
}

// ---------------- K4: fused replay + hs + gelu + LayerNorm (vectorized x4) -----
__global__ __launch_bounds__(256) void k_scanln(const u16* __restrict__ ufr,
                                                const float* __restrict__ S,
                                                const float* __restrict__ x,
                                                const float* __restrict__ lnw,
                                                const float* __restrict__ lnb,
                                                float* __restrict__ out) {
  const int j = blockIdx.x >> 3;                  // chunk 0..127
  const int b = blockIdx.x & 7;                   // batch
  const int tid = threadIdx.x;                    // 0..255
  const int d0 = tid << 2;
  const int lane = tid & 63, wid = tid >> 6;      // 4 waves

  float4 c4  = *(const float4*)&S[j * NCHAIN + b * DIM + d0];
  float c0v = c4.x, c1v = c4.y, c2v = c4.z, c3v = c4.w;
  const float4 wv = *(const float4*)(lnw + d0);
  const float4 bv = *(const float4*)(lnb + d0);

  const u16*   pu = ufr + (size_t)((j * LCHUNK) * BATCH + b) * N3 + d0;
  const float* px = x   + (size_t)((j * LCHUNK) * BATCH + b) * DIM + d0;
  float*       po = out + (size_t)((j * LCHUNK) * BATCH + b) * DIM + d0;

  __shared__ float red1[2][4], red2[2][4];

  us4 cu = *(const us4*)(pu);
  us4 cf = *(const us4*)(pu + DIM);
  us4 cr = *(const us4*)(pu + 2 * DIM);
  float4 cx = *(const float4*)px;

  for (int t = 0; t < LCHUNK; ++t) {
    const size_t advU = (t < LCHUNK - 1) ? (size_t)BATCH * N3 : 0;
    const size_t advX = (t < LCHUNK - 1) ? (size_t)BATCH * DIM : 0;
    us4 nu = *(const us4*)(pu + advU);
    us4 nf = *(const us4*)(pu + advU + DIM);
    us4 nr = *(const us4*)(pu + advU + 2 * DIM);
    float4 nx = *(const float4*)(px + advX);

    float g0, g1, g2, g3;
    {
      float f = b2f(cf.x); c0v = f * c0v + (1.f - f) * b2f(cu.x);
      float rr = b2f(cr.x);
      float hs = rr * tanhf(c0v) + (1.f - rr) * cx.x;
      g0 = 0.5f * hs * (1.f + erff(hs * 0.70710678118654752f));
    }
    {
      float f = b2f(cf.y); c1v = f * c1v + (1.f - f) * b2f(cu.y);
      float rr = b2f(cr.y);
      float hs = rr * tanhf(c1v) + (1.f - rr) * cx.y;
      g1 = 0.5f * hs * (1.f + erff(hs * 0.70710678118654752f));
    }
    {
      float f = b2f(cf.z); c2v = f * c2v + (1.f - f) * b2f(cu.z);
      float rr = b2f(cr.z);
      float hs = rr * tanhf(c2v) + (1.f - rr) * cx.z;
      g2 = 0.5f * hs * (1.f + erff(hs * 0.70710678118654752f));
    }
    {
      float f = b2f(cf.w); c3v = f * c3v + (1.f - f) * b2f(cu.w);
      float rr = b2f(cr.w);
      float hs = rr * tanhf(c3v) + (1.f - rr) * cx.w;
      g3 = 0.5f * hs * (1.f + erff(hs * 0.70710678118654752f));
    }

    float s1 = g0 + g1 + g2 + g3;
    float s2 = g0 * g0 + g1 * g1 + g2 * g2 + g3 * g3;
#pragma unroll
    for (int off = 32; off > 0; off >>= 1) {
      s1 += __shfl_down(s1, off, 64);
      s2 += __shfl_down(s2, off, 64);
    }
    const int pb = t & 1;
    if (lane == 0) { red1[pb][wid] = s1; red2[pb][wid] = s2; }
    __syncthreads();
    float S1 = red1[pb][0] + red1[pb][1] + red1[pb][2] + red1[pb][3];
    float S2 = red2[pb][0] + red2[pb][1] + red2[pb][2] + red2[pb][3];
    float mu  = S1 * (1.f / DIM);
    float var = S2 * (1.f / DIM) - mu * mu;
    float inv = rsqrtf(var + 1e-5f);
    float4 o;
    o.x = (g0 - mu) * inv * wv.x + bv.x;
    o.y = (g1 - mu) * inv * wv.y + bv.y;
    o.z = (g2 - mu) * inv * wv.z + bv.z;
    o.w = (g3 - mu) * inv * wv.w + bv.w;
    *(float4*)po = o;

    cu = nu; cf = nf; cr = nr; cx = nx;
    pu += BATCH * N3;
    px += BATCH * DIM;
    po += BATCH * DIM;
  }
}

extern "C" void kernel_launch(void* const* d_in, const int* in_sizes, int n_in,
                              void* d_out, int out_size, void* d_ws, size_t ws_size,
                              hipStream_t stream) {
  (void)in_sizes; (void)n_in; (void)out_size;
  const float* x   = (const float*)d_in[0];
  const float* c0  = (const float*)d_in[1];
  const float* W   = (const float*)d_in[2];
  const float* lnw = (const float*)d_in[3];
  const float* lnb = (const float*)d_in[4];
  float* out   = (float*)d_out;                   // (L,B,D) f32
  float* lastc = out + (size_t)ROWS * DIM;        // (B,D)   f32

  char* ws = (char*)d_ws;

  u16* ufr; float *P, *V, *S;
  const size_t FULL_NEED = 140509184;             // apk + wpk + ufr (P/V/S alias apk)
  if (ws_size >= FULL_NEED) {
    u16* apk = (u16*)ws;                          // 33,554,432 B (dead after GEMM)
    u16* wpk = (u16*)(ws + 33554432);             //  6,291,456 B
    ufr = (u16*)(ws + 39845888);                  // 100,663,296 B
    P   = (float*)ws;                             // alias apk region (4 MB each)
    V   = (float*)(ws + 4194304);
    S   = (float*)(ws + 8388608);
    k_pack<<<2048, 256, 0, stream>>>(x, W, apk, wpk);
    k_gemm_v6b<<<1536, 512, 0, stream>>>(apk, wpk, ufr);
  } else {
    ufr = (u16*)ws;
    P   = (float*)(ws + 100663296);
    V   = (float*)(ws + 104857600);
    S   = (float*)(ws + 109051904);
    dim3 g1(N3 / 128, ROWS / 128);
    k_gemm_reg<<<g1, 256, 0, stream>>>(x, W, ufr);
  }

  k_scanA<<<1024, 256, 0, stream>>>(ufr, P, V);
  k_scanB<<<NCHAIN / 256, 256, 0, stream>>>(c0, P, V, S, lastc);
  k_scanln<<<NCHUNK * BATCH, 256, 0, stream>>>(ufr, S, x, lnw, lnb, out);
}